// Round 15
// baseline (341.713 us; speedup 1.0000x reference)
//
#include <hip/hip_runtime.h>

typedef _Float16 f16;
typedef __fp16 h16x2 __attribute__((ext_vector_type(2)));
typedef f16 f16x8 __attribute__((ext_vector_type(8)));
typedef float f32x4 __attribute__((ext_vector_type(4)));

#define HW    128
#define NPIX  16384      // 128*128
#define CDIM  256
#define DLOI  128
#define LROWS 40000      // B*L
#define DFC   1024
#define KP1   1088       // fc1 K (1032) padded to 17*64

// ---------------- conv1x1 as LDS-staged MFMA GEMM: x[b][pix][d] (f16)
// feature[c][pix] staged via width-4 global_load_lds with per-lane source
// XOR-transpose: As[pix][c_slot], c = c_slot ^ ((pix&7)<<2)  (rule 21/m173:
// LDS dest lane-linear, global src per-lane). Frag reads = 2x ds_read_b128,
// 2-way banks (free). W staged with slot^(d&7) swizzle, width-16.
__global__ __launch_bounds__(256, 4) void conv1x1_kernel(
    const float* __restrict__ feature, const float* __restrict__ Wfc,
    const float* __restrict__ bfc, f16* __restrict__ x) {
  __shared__ float As[32 * 128];     // [pix 0..127][c_slot 0..31], 16 KB
  __shared__ float Bs[128 * 32];     // [d 0..127][c 0..31 swizzled], 16 KB
  const int tid = threadIdx.x;
  const int l = tid & 63;
  const int w = tid >> 6;
  const int bid = blockIdx.x;        // 0..1023
  const int b = bid & 7;             // batch -> XCD pin (matches sample_kernel)
  const int pix0 = (bid >> 3) * 128;
  const int wr = (w >> 1) * 64, wc = (w & 1) * 64;
  const int lrow = l & 15, g4 = l >> 4;

  const float* fb = feature + (size_t)b * CDIM * NPIX;
  f32x4 acc[4][4] = {};

  // staging thread-constants
  const int a_cslot = tid & 31;                       // c_slot
  const int a_pixl  = tid >> 5;                       // pix low (0..7), const mod 8
  const int a_c     = a_cslot ^ (a_pixl << 2);        // actual c offset 0..31
  const int b_dl    = tid >> 3;                       // d low 0..31
  const int b_coff  = ((tid & 7) ^ (b_dl & 7)) * 4;   // source c offset 0..28

  // read-side thread-constants (X = (pix&7)<<2 = (lrow&7)<<2)
  const int aX = (lrow & 7) << 2;
  const int s1 = (g4 * 8) ^ aX;                       // aligned-4 slot bases
  const int s2 = (g4 * 8 + 4) ^ aX;

  for (int kt = 0; kt < 8; ++kt) {
    const int kb = kt * 32;
    __syncthreads();
    // A: 16 passes width-4; dest dword = pass*256 + tid (lane-linear)
    {
      const float* g = fb + (size_t)(kb + a_c) * NPIX + pix0 + a_pixl;
      float* d = As + a_pixl * 32 + a_cslot;
#pragma unroll
      for (int pass = 0; pass < 16; ++pass) {
        __builtin_amdgcn_global_load_lds(
            (const __attribute__((address_space(1))) void*)g,
            (__attribute__((address_space(3))) void*)d, 4, 0, 0);
        g += 8;            // pix += 8
        d += 256;          // 8 rows * 32 slots
      }
    }
    // B: 4 passes width-16; dest slot16 = pass*256 + tid (lane-linear)
    {
      const float* g = Wfc + (size_t)b_dl * CDIM + kb + b_coff;
      float* d = Bs + b_dl * 32 + (tid & 7) * 4;
#pragma unroll
      for (int pass = 0; pass < 4; ++pass) {
        __builtin_amdgcn_global_load_lds(
            (const __attribute__((address_space(1))) void*)g,
            (__attribute__((address_space(3))) void*)d, 16, 0, 0);
        g += (size_t)32 * CDIM;   // d += 32
        d += 32 * 32;
      }
    }
    __syncthreads();

    // B-frags (W): lane d = wc + n*16 + lrow, c-quads 2g4, 2g4+1
    f16x8 bf[4];
#pragma unroll
    for (int n = 0; n < 4; ++n) {
      const int d = wc + n * 16 + lrow;
      const int c1 = (2 * g4) ^ (d & 7);
      const int c2 = (2 * g4 + 1) ^ (d & 7);
      f32x4 lo = *(const f32x4*)(Bs + d * 32 + c1 * 4);
      f32x4 hi = *(const f32x4*)(Bs + d * 32 + c2 * 4);
      union { f16x8 v; h16x2 h[4]; } u;
      u.h[0] = __builtin_amdgcn_cvt_pkrtz(lo[0], lo[1]);
      u.h[1] = __builtin_amdgcn_cvt_pkrtz(lo[2], lo[3]);
      u.h[2] = __builtin_amdgcn_cvt_pkrtz(hi[0], hi[1]);
      u.h[3] = __builtin_amdgcn_cvt_pkrtz(hi[2], hi[3]);
      bf[n] = u.v;
    }
    // A-frags (feature) + MFMA
#pragma unroll
    for (int m = 0; m < 4; ++m) {
      const int pix = wr + m * 16 + lrow;
      f32x4 lo = *(const f32x4*)(As + pix * 32 + s1);
      f32x4 hi = *(const f32x4*)(As + pix * 32 + s2);
      union { f16x8 v; h16x2 h[4]; } u;
      u.h[0] = __builtin_amdgcn_cvt_pkrtz(lo[0], lo[1]);
      u.h[1] = __builtin_amdgcn_cvt_pkrtz(lo[2], lo[3]);
      u.h[2] = __builtin_amdgcn_cvt_pkrtz(hi[0], hi[1]);
      u.h[3] = __builtin_amdgcn_cvt_pkrtz(hi[2], hi[3]);
#pragma unroll
      for (int n = 0; n < 4; ++n)
        acc[m][n] = __builtin_amdgcn_mfma_f32_16x16x32_f16(u.v, bf[n], acc[m][n], 0, 0, 0);
    }
  }

#pragma unroll
  for (int m = 0; m < 4; ++m) {
#pragma unroll
    for (int r = 0; r < 4; ++r) {
      const int pix = pix0 + wr + m * 16 + g4 * 4 + r;
      f16* xr = x + ((size_t)b * NPIX + pix) * DLOI;
#pragma unroll
      for (int n = 0; n < 4; ++n) {
        const int d = wc + n * 16 + lrow;
        xr[d] = (f16)(acc[m][n][r] + bfc[d]);
      }
    }
  }
}

// ---------------- sampling + bilinear + maxpool(4) + concat -> z[40000][1088] fp16
__global__ __launch_bounds__(256) void sample_kernel(
    const f16* __restrict__ x, const float* __restrict__ p,
    const float* __restrict__ feat, f16* __restrict__ z) {
  const int tid = threadIdx.x;
  const int wv = tid >> 6;
  const int lane = tid & 63;
  const int sub = lane >> 4;           // pool group within half
  const int cl = lane & 15;            // channel block (8 ch)
  const int bid = blockIdx.x;          // 0..9999
  const int b = bid & 7;               // batch -> XCD pin
  const int row = b * 5000 + (bid >> 3) * 4 + wv;

  const float4 pe = *(const float4*)&p[(size_t)row * 4]; // p0x p0y p1x p1y
  const size_t bb = (size_t)b * NPIX;
  f16* zr = z + (size_t)row * KP1;

#pragma unroll
  for (int gh = 0; gh < 2; ++gh) {
    const int g = gh * 4 + sub;        // pool group 0..7
    float acc[8];
#pragma unroll
    for (int ci = 0; ci < 8; ++ci) acc[ci] = -1e30f;
#pragma unroll
    for (int pt = 0; pt < 4; ++pt) {
      const int t = g * 4 + pt;
      const float lam = (float)t * (1.0f / 31.0f);
      const float px = pe.x * lam + pe.z * (1.f - lam) - 0.5f;
      const float py = pe.y * lam + pe.w * (1.f - lam) - 0.5f;
      const float px0 = fminf(fmaxf(floorf(px), 0.f), 127.f);
      const float py0 = fminf(fmaxf(floorf(py), 0.f), 127.f);
      const float px1 = fminf(px0 + 1.f, 127.f);
      const float py1 = fminf(py0 + 1.f, 127.f);
      const int ix0 = (int)px0, iy0 = (int)py0, ix1 = (int)px1, iy1 = (int)py1;
      const float w00 = (px1 - px) * (py1 - py);
      const float w10 = (px - px0) * (py1 - py);
      const float w01 = (px1 - px) * (py - py0);
      const float w11 = (px - px0) * (py - py0);

      const f16* r00 = x + (bb + ix0 * HW + iy0) * DLOI + cl * 8;
      const f16* r10 = x + (bb + ix1 * HW + iy0) * DLOI + cl * 8;
      const f16* r01 = x + (bb + ix0 * HW + iy1) * DLOI + cl * 8;
      const f16* r11 = x + (bb + ix1 * HW + iy1) * DLOI + cl * 8;
      f16x8 a  = *(const f16x8*)r00;
      f16x8 bq = *(const f16x8*)r10;
      f16x8 cq = *(const f16x8*)r01;
      f16x8 dq = *(const f16x8*)r11;
#pragma unroll
      for (int ci = 0; ci < 8; ++ci) {
        float m = w00 * (float)a[ci] + w10 * (float)bq[ci] +
                  w01 * (float)cq[ci] + w11 * (float)dq[ci];
        acc[ci] = fmaxf(acc[ci], m);
      }
    }
    f16x8 o;
#pragma unroll
    for (int ci = 0; ci < 8; ++ci) o[ci] = (f16)acc[ci];
    *(f16x8*)(zr + g * 128 + cl * 8) = o;
  }
  if (lane < 8) zr[1024 + lane] = (f16)feat[(size_t)row * 8 + lane];
  else if (lane < 36) *(unsigned int*)((char*)zr + 2064 + (lane - 8) * 4) = 0u;
}

// ---------------- weight transpose + fp16 + K-pad (+ optional k-permute for z layout)
__global__ __launch_bounds__(256) void wtrans_kernel(
    const float* __restrict__ W, f16* __restrict__ Wt, int K, int ldt, int permute) {
  __shared__ float t[32][33];
  const int tx = threadIdx.x & 31, ty = threadIdx.x >> 5;
#pragma unroll
  for (int i = 0; i < 4; ++i) {
    int kd = blockIdx.y * 32 + ty + i * 8;
    int ks = (permute && kd < 1024) ? ((kd & 127) * 8 + (kd >> 7)) : kd;
    int n = blockIdx.x * 32 + tx;
    t[ty + i * 8][tx] = (ks < K) ? W[(size_t)ks * DFC + n] : 0.f;
  }
  __syncthreads();
#pragma unroll
  for (int i = 0; i < 4; ++i) {
    int n = blockIdx.x * 32 + ty + i * 8;
    int k = blockIdx.y * 32 + tx;
    Wt[(size_t)n * ldt + k] = (f16)t[tx][ty + i * 8];
  }
}

// ================= 256x128-tile GEMM main loop, 8 waves (512 thr).
// FROZEN (r12): conflict-free 16x16x32, 2-barrier K-loop, 48KB LDS,
// 3-4 blocks/CU, ~860 TF (2-barrier-family ceiling; r7/r8/r13 showed
// deep-pipeline variants regress at 1 block/CU).
#define GEMM_MAIN_LOOP(A_, Bt_, M_, ksteps_, lda_)                              \
  __shared__ f16 As[256 * 64];                                                  \
  __shared__ f16 Bs[128 * 64];                                                  \
  const int tid = threadIdx.x;                                                  \
  const int l = tid & 63;                                                       \
  const int w = tid >> 6;                                                       \
  const int nwg = gridDim.x;            /* 1256 = 8*157 */                      \
  const int s = (blockIdx.x & 7) * (nwg >> 3) + (blockIdx.x >> 3);              \
  const int m0 = (s >> 3) * 256;                                                \
  const int n0 = (s & 7) * 128;                                                 \
  const int wr = (w >> 1) * 64, wc = (w & 1) * 64;                              \
  const int srow = tid >> 3;            /* 0..63 */                             \
  const int slot = tid & 7;                                                     \
  const int lrow = l & 15, g4 = l >> 4;                                         \
  f32x4 acc[4][4] = {};                                                         \
  for (int kt = 0; kt < ksteps_; ++kt) {                                        \
    const int kb = kt * 64;                                                     \
    __syncthreads();                                                            \
    _Pragma("unroll")                                                           \
    for (int c = 0; c < 4; ++c) {                                               \
      int row = c * 64 + srow;                                                  \
      int arow = m0 + row; if (arow >= M_) arow = M_ - 1;                       \
      const f16* g = A_ + (size_t)arow * lda_ + kb + ((slot ^ (row & 7)) * 8);  \
      __builtin_amdgcn_global_load_lds(                                         \
          (const __attribute__((address_space(1))) void*)g,                     \
          (__attribute__((address_space(3))) void*)(As + row * 64 + slot * 8),  \
          16, 0, 0);                                                            \
    }                                                                           \
    _Pragma("unroll")                                                           \
    for (int c = 0; c < 2; ++c) {                                               \
      int row = c * 64 + srow;                                                  \
      const f16* g = Bt_ + (size_t)(n0 + row) * lda_ + kb + ((slot ^ (row & 7)) * 8); \
      __builtin_amdgcn_global_load_lds(                                         \
          (const __attribute__((address_space(1))) void*)g,                     \
          (__attribute__((address_space(3))) void*)(Bs + row * 64 + slot * 8),  \
          16, 0, 0);                                                            \
    }                                                                           \
    __syncthreads();                                                            \
    _Pragma("unroll")                                                           \
    for (int kh = 0; kh < 2; ++kh) {                                            \
      f16x8 af[4], bf[4];                                                       \
      _Pragma("unroll")                                                         \
      for (int m = 0; m < 4; ++m) {                                             \
        int row = wr + m * 16 + lrow;                                           \
        int sl = (g4 + 4 * kh) ^ (row & 7);                                     \
        af[m] = *(const f16x8*)(As + row * 64 + sl * 8);                        \
      }                                                                         \
      _Pragma("unroll")                                                         \
      for (int n = 0; n < 4; ++n) {                                             \
        int row = wc + n * 16 + lrow;                                           \
        int sl = (g4 + 4 * kh) ^ (row & 7);                                     \
        bf[n] = *(const f16x8*)(Bs + row * 64 + sl * 8);                        \
      }                                                                         \
      _Pragma("unroll")                                                         \
      for (int m = 0; m < 4; ++m)                                               \
        _Pragma("unroll")                                                       \
        for (int n = 0; n < 4; ++n)                                             \
          acc[m][n] = __builtin_amdgcn_mfma_f32_16x16x32_f16(af[m], bf[n], acc[m][n], 0, 0, 0); \
    }                                                                           \
  }

// ---------------- GEMM1: C = relu_f16(A @ Bt^T + bias), h1 output
__global__ __launch_bounds__(512, 4) void gemm_f16(
    const f16* __restrict__ A, const f16* __restrict__ Bt,
    const float* __restrict__ bias, f16* __restrict__ C,
    int M, int ksteps, int lda) {
  GEMM_MAIN_LOOP(A, Bt, M, ksteps, lda)

  const int ocol0 = n0 + wc + lrow;
  const int orow0 = m0 + wr + g4 * 4;
#pragma unroll
  for (int m = 0; m < 4; ++m) {
#pragma unroll
    for (int r = 0; r < 4; ++r) {
      int orow = orow0 + m * 16 + r;
      if (orow >= M) continue;
      f16* crow = C + (size_t)orow * DFC;
#pragma unroll
      for (int n = 0; n < 4; ++n) {
        int col = ocol0 + n * 16;
        float v = acc[m][n][r] + bias[col];
        crow[col] = (f16)fmaxf(v, 0.f);
      }
    }
  }
}

// ---------------- GEMM2 with fused fc3: out[m] += sum_col relu(h2)*W3[col]
__global__ __launch_bounds__(512, 4) void gemm2_fc3(
    const f16* __restrict__ A, const f16* __restrict__ Bt,
    const float* __restrict__ bias, const float* __restrict__ W3,
    float* __restrict__ out, int M, int ksteps, int lda) {
  GEMM_MAIN_LOOP(A, Bt, M, ksteps, lda)

  const int ocol0 = n0 + wc + lrow;
  const int orow0 = m0 + wr + g4 * 4;
  float b4[4], w3v[4];
#pragma unroll
  for (int n = 0; n < 4; ++n) {
    b4[n] = bias[ocol0 + n * 16];
    w3v[n] = W3[ocol0 + n * 16];
  }
#pragma unroll
  for (int m = 0; m < 4; ++m) {
#pragma unroll
    for (int r = 0; r < 4; ++r) {
      float sacc = 0.f;
#pragma unroll
      for (int n = 0; n < 4; ++n) {
        float v = fmaxf(acc[m][n][r] + b4[n], 0.f);
        sacc += v * w3v[n];
      }
      sacc += __shfl_xor(sacc, 1);
      sacc += __shfl_xor(sacc, 2);
      sacc += __shfl_xor(sacc, 4);
      sacc += __shfl_xor(sacc, 8);
      int orow = orow0 + m * 16 + r;
      if (lrow == 0 && orow < M) atomicAdd(&out[orow], sacc);
    }
  }
}

// ---------------- init out with b3 (also clears harness poison)
__global__ __launch_bounds__(256) void fill_out(
    float* __restrict__ out, const float* __restrict__ b3, int n) {
  int i = blockIdx.x * 256 + threadIdx.x;
  if (i < n) out[i] = b3[0];
}

extern "C" void kernel_launch(void* const* d_in, const int* in_sizes, int n_in,
                              void* d_out, int out_size, void* d_ws, size_t ws_size,
                              hipStream_t stream) {
  const float* feature = (const float*)d_in[0];
  const float* p       = (const float*)d_in[1];
  const float* feat    = (const float*)d_in[2];
  const float* W_fc1   = (const float*)d_in[3];
  const float* b_fc1   = (const float*)d_in[4];
  const float* W1      = (const float*)d_in[5];
  const float* b1      = (const float*)d_in[6];
  const float* W2      = (const float*)d_in[7];
  const float* b2      = (const float*)d_in[8];
  const float* W3      = (const float*)d_in[9];
  const float* b3      = (const float*)d_in[10];
  float* out = (float*)d_out;

  char* ws = (char*)d_ws;
  f16* x   = (f16*)(ws + 0);                    //  33,554,432 B
  f16* z   = (f16*)(ws + 33554432ULL);          //  87,040,000 B (40000x1088)
  f16* h1  = (f16*)(ws + 120594432ULL);         //  81,920,000 B (40000x1024)
  f16* W1t = (f16*)(ws + 202514432ULL);         //   2,228,224 B (1024x1088)
  f16* W2t = (f16*)(ws + 204742656ULL);         //   2,097,152 B (1024x1024)

  hipLaunchKernelGGL(wtrans_kernel, dim3(32, 34), dim3(256), 0, stream,
                     W1, W1t, 1032, KP1, 1);
  hipLaunchKernelGGL(wtrans_kernel, dim3(32, 32), dim3(256), 0, stream,
                     W2, W2t, 1024, 1024, 0);
  hipLaunchKernelGGL(conv1x1_kernel, dim3(1024), dim3(256), 0, stream,
                     feature, W_fc1, b_fc1, x);
  hipLaunchKernelGGL(sample_kernel, dim3(10000), dim3(256), 0, stream,
                     x, p, feat, z);
  hipLaunchKernelGGL(gemm_f16, dim3(1256), dim3(512), 0, stream,
                     z, W1t, b1, h1, LROWS, KP1 / 64, KP1);
  hipLaunchKernelGGL(fill_out, dim3(157), dim3(256), 0, stream,
                     out, b3, LROWS);
  hipLaunchKernelGGL(gemm2_fc3, dim3(1256), dim3(512), 0, stream,
                     h1, W2t, b2, W3, out, LROWS, DFC / 64, DFC);
}

// Round 16
// 328.939 us; speedup vs baseline: 1.0388x; 1.0388x over previous
//
#include <hip/hip_runtime.h>

typedef _Float16 f16;
typedef __fp16 h16x2 __attribute__((ext_vector_type(2)));
typedef f16 f16x8 __attribute__((ext_vector_type(8)));
typedef float f32x4 __attribute__((ext_vector_type(4)));

#define HW    128
#define NPIX  16384      // 128*128
#define CDIM  256
#define DLOI  128
#define LROWS 40000      // B*L
#define DFC   1024
#define KP1   1088       // fc1 K (1032) padded to 17*64

// ---------------- W_fc1 f32 -> f16 cast (layout already [d][c] = Bt)
__global__ __launch_bounds__(256) void wcast_kernel(
    const float* __restrict__ W, f16* __restrict__ Wc, int n) {
  int i = blockIdx.x * 256 + threadIdx.x;
  if (i < n) Wc[i] = (f16)W[i];
}

// ---------------- feature [b][c][pix] f32 -> ft [b][pix][c] f16
// 64x64 LDS tile; float4 coalesced reads, f16x8 coalesced writes,
// both LDS phases 2-way bank aliased (free). batch = bid&7 (XCD pin).
__global__ __launch_bounds__(256) void transpose_kernel(
    const float* __restrict__ feature, f16* __restrict__ ft) {
  __shared__ float t[64][65];
  const int tid = threadIdx.x;
  const int bid = blockIdx.x;            // 8192 = 1024 tiles x 8 batches
  const int b = bid & 7;
  const int tile = bid >> 3;             // 256 pix-tiles x 4 c-tiles
  const int pix0 = (tile & 255) * 64;
  const int c0 = (tile >> 8) * 64;

  const float* fb = feature + ((size_t)b * CDIM + c0) * NPIX + pix0;
#pragma unroll
  for (int i = 0; i < 4; ++i) {
    const int c = (tid >> 4) + i * 16;
    const int px = (tid & 15) * 4;
    float4 v = *(const float4*)(fb + (size_t)c * NPIX + px);
    t[c][px] = v.x; t[c][px + 1] = v.y; t[c][px + 2] = v.z; t[c][px + 3] = v.w;
  }
  __syncthreads();
  f16* fo = ft + ((size_t)b * NPIX + pix0) * CDIM + c0;
#pragma unroll
  for (int i = 0; i < 2; ++i) {
    const int px = (tid >> 3) + i * 32;
    const int co = (tid & 7) * 8;
    float v[8];
#pragma unroll
    for (int j = 0; j < 8; ++j) v[j] = t[co + j][px];
    union { f16x8 o; h16x2 h[4]; } u;
    u.h[0] = __builtin_amdgcn_cvt_pkrtz(v[0], v[1]);
    u.h[1] = __builtin_amdgcn_cvt_pkrtz(v[2], v[3]);
    u.h[2] = __builtin_amdgcn_cvt_pkrtz(v[4], v[5]);
    u.h[3] = __builtin_amdgcn_cvt_pkrtz(v[6], v[7]);
    *(f16x8*)(fo + (size_t)px * CDIM + co) = u.o;
  }
}

// ---------------- conv as frozen-structure GEMM: x[pix][d] = ft[pix][c] @ W[d][c]^T + bias
// M=131072 (exact 512 tiles), N=128 (one n-tile), K=256 (4 ksteps). No relu.
__global__ __launch_bounds__(512, 4) void conv_gemm(
    const f16* __restrict__ A, const f16* __restrict__ Bt,
    const float* __restrict__ bias, f16* __restrict__ C) {
  __shared__ f16 As[256 * 64];
  __shared__ f16 Bs[128 * 64];
  const int tid = threadIdx.x;
  const int l = tid & 63;
  const int w = tid >> 6;
  const int s = (blockIdx.x & 7) * 64 + (blockIdx.x >> 3);  // 512 WGs, batch==XCD
  const int m0 = s * 256;
  const int wr = (w >> 1) * 64, wc = (w & 1) * 64;
  const int srow = tid >> 3;
  const int slot = tid & 7;
  const int lrow = l & 15, g4 = l >> 4;
  f32x4 acc[4][4] = {};

  for (int kt = 0; kt < 4; ++kt) {
    const int kb = kt * 64;
    __syncthreads();
#pragma unroll
    for (int c = 0; c < 4; ++c) {
      int row = c * 64 + srow;
      const f16* g = A + (size_t)(m0 + row) * CDIM + kb + ((slot ^ (row & 7)) * 8);
      __builtin_amdgcn_global_load_lds(
          (const __attribute__((address_space(1))) void*)g,
          (__attribute__((address_space(3))) void*)(As + row * 64 + slot * 8),
          16, 0, 0);
    }
#pragma unroll
    for (int c = 0; c < 2; ++c) {
      int row = c * 64 + srow;
      const f16* g = Bt + (size_t)row * CDIM + kb + ((slot ^ (row & 7)) * 8);
      __builtin_amdgcn_global_load_lds(
          (const __attribute__((address_space(1))) void*)g,
          (__attribute__((address_space(3))) void*)(Bs + row * 64 + slot * 8),
          16, 0, 0);
    }
    __syncthreads();
#pragma unroll
    for (int kh = 0; kh < 2; ++kh) {
      f16x8 af[4], bf[4];
#pragma unroll
      for (int m = 0; m < 4; ++m) {
        int row = wr + m * 16 + lrow;
        int sl = (g4 + 4 * kh) ^ (row & 7);
        af[m] = *(const f16x8*)(As + row * 64 + sl * 8);
      }
#pragma unroll
      for (int n = 0; n < 4; ++n) {
        int row = wc + n * 16 + lrow;
        int sl = (g4 + 4 * kh) ^ (row & 7);
        bf[n] = *(const f16x8*)(Bs + row * 64 + sl * 8);
      }
#pragma unroll
      for (int m = 0; m < 4; ++m)
#pragma unroll
        for (int n = 0; n < 4; ++n)
          acc[m][n] = __builtin_amdgcn_mfma_f32_16x16x32_f16(af[m], bf[n], acc[m][n], 0, 0, 0);
    }
  }

  const int ocol0 = wc + lrow;
  const int orow0 = m0 + wr + g4 * 4;
#pragma unroll
  for (int m = 0; m < 4; ++m) {
#pragma unroll
    for (int r = 0; r < 4; ++r) {
      f16* crow = C + (size_t)(orow0 + m * 16 + r) * DLOI;
#pragma unroll
      for (int n = 0; n < 4; ++n) {
        int col = ocol0 + n * 16;
        crow[col] = (f16)(acc[m][n][r] + bias[col]);
      }
    }
  }
}

// ---------------- sampling + bilinear + maxpool(4) + concat -> z[40000][1088] fp16
__global__ __launch_bounds__(256) void sample_kernel(
    const f16* __restrict__ x, const float* __restrict__ p,
    const float* __restrict__ feat, f16* __restrict__ z) {
  const int tid = threadIdx.x;
  const int wv = tid >> 6;
  const int lane = tid & 63;
  const int sub = lane >> 4;           // pool group within half
  const int cl = lane & 15;            // channel block (8 ch)
  const int bid = blockIdx.x;          // 0..9999
  const int b = bid & 7;               // batch -> XCD pin
  const int row = b * 5000 + (bid >> 3) * 4 + wv;

  const float4 pe = *(const float4*)&p[(size_t)row * 4]; // p0x p0y p1x p1y
  const size_t bb = (size_t)b * NPIX;
  f16* zr = z + (size_t)row * KP1;

#pragma unroll
  for (int gh = 0; gh < 2; ++gh) {
    const int g = gh * 4 + sub;        // pool group 0..7
    float acc[8];
#pragma unroll
    for (int ci = 0; ci < 8; ++ci) acc[ci] = -1e30f;
#pragma unroll
    for (int pt = 0; pt < 4; ++pt) {
      const int t = g * 4 + pt;
      const float lam = (float)t * (1.0f / 31.0f);
      const float px = pe.x * lam + pe.z * (1.f - lam) - 0.5f;
      const float py = pe.y * lam + pe.w * (1.f - lam) - 0.5f;
      const float px0 = fminf(fmaxf(floorf(px), 0.f), 127.f);
      const float py0 = fminf(fmaxf(floorf(py), 0.f), 127.f);
      const float px1 = fminf(px0 + 1.f, 127.f);
      const float py1 = fminf(py0 + 1.f, 127.f);
      const int ix0 = (int)px0, iy0 = (int)py0, ix1 = (int)px1, iy1 = (int)py1;
      const float w00 = (px1 - px) * (py1 - py);
      const float w10 = (px - px0) * (py1 - py);
      const float w01 = (px1 - px) * (py - py0);
      const float w11 = (px - px0) * (py - py0);

      const f16* r00 = x + (bb + ix0 * HW + iy0) * DLOI + cl * 8;
      const f16* r10 = x + (bb + ix1 * HW + iy0) * DLOI + cl * 8;
      const f16* r01 = x + (bb + ix0 * HW + iy1) * DLOI + cl * 8;
      const f16* r11 = x + (bb + ix1 * HW + iy1) * DLOI + cl * 8;
      f16x8 a  = *(const f16x8*)r00;
      f16x8 bq = *(const f16x8*)r10;
      f16x8 cq = *(const f16x8*)r01;
      f16x8 dq = *(const f16x8*)r11;
#pragma unroll
      for (int ci = 0; ci < 8; ++ci) {
        float m = w00 * (float)a[ci] + w10 * (float)bq[ci] +
                  w01 * (float)cq[ci] + w11 * (float)dq[ci];
        acc[ci] = fmaxf(acc[ci], m);
      }
    }
    f16x8 o;
#pragma unroll
    for (int ci = 0; ci < 8; ++ci) o[ci] = (f16)acc[ci];
    *(f16x8*)(zr + g * 128 + cl * 8) = o;
  }
  if (lane < 8) zr[1024 + lane] = (f16)feat[(size_t)row * 8 + lane];
  else if (lane < 36) *(unsigned int*)((char*)zr + 2064 + (lane - 8) * 4) = 0u;
}

// ---------------- weight transpose + fp16 + K-pad (+ optional k-permute for z layout)
__global__ __launch_bounds__(256) void wtrans_kernel(
    const float* __restrict__ W, f16* __restrict__ Wt, int K, int ldt, int permute) {
  __shared__ float t[32][33];
  const int tx = threadIdx.x & 31, ty = threadIdx.x >> 5;
#pragma unroll
  for (int i = 0; i < 4; ++i) {
    int kd = blockIdx.y * 32 + ty + i * 8;
    int ks = (permute && kd < 1024) ? ((kd & 127) * 8 + (kd >> 7)) : kd;
    int n = blockIdx.x * 32 + tx;
    t[ty + i * 8][tx] = (ks < K) ? W[(size_t)ks * DFC + n] : 0.f;
  }
  __syncthreads();
#pragma unroll
  for (int i = 0; i < 4; ++i) {
    int n = blockIdx.x * 32 + ty + i * 8;
    int k = blockIdx.y * 32 + tx;
    Wt[(size_t)n * ldt + k] = (f16)t[tx][ty + i * 8];
  }
}

// ================= 256x128-tile GEMM main loop, 8 waves (512 thr).
// FROZEN (r12): conflict-free 16x16x32, 2-barrier K-loop, 48KB LDS,
// 3-4 blocks/CU, ~860 TF (2-barrier-family ceiling).
#define GEMM_MAIN_LOOP(A_, Bt_, M_, ksteps_, lda_)                              \
  __shared__ f16 As[256 * 64];                                                  \
  __shared__ f16 Bs[128 * 64];                                                  \
  const int tid = threadIdx.x;                                                  \
  const int l = tid & 63;                                                       \
  const int w = tid >> 6;                                                       \
  const int nwg = gridDim.x;            /* 1256 = 8*157 */                      \
  const int s = (blockIdx.x & 7) * (nwg >> 3) + (blockIdx.x >> 3);              \
  const int m0 = (s >> 3) * 256;                                                \
  const int n0 = (s & 7) * 128;                                                 \
  const int wr = (w >> 1) * 64, wc = (w & 1) * 64;                              \
  const int srow = tid >> 3;            /* 0..63 */                             \
  const int slot = tid & 7;                                                     \
  const int lrow = l & 15, g4 = l >> 4;                                         \
  f32x4 acc[4][4] = {};                                                         \
  for (int kt = 0; kt < ksteps_; ++kt) {                                        \
    const int kb = kt * 64;                                                     \
    __syncthreads();                                                            \
    _Pragma("unroll")                                                           \
    for (int c = 0; c < 4; ++c) {                                               \
      int row = c * 64 + srow;                                                  \
      int arow = m0 + row; if (arow >= M_) arow = M_ - 1;                       \
      const f16* g = A_ + (size_t)arow * lda_ + kb + ((slot ^ (row & 7)) * 8);  \
      __builtin_amdgcn_global_load_lds(                                         \
          (const __attribute__((address_space(1))) void*)g,                     \
          (__attribute__((address_space(3))) void*)(As + row * 64 + slot * 8),  \
          16, 0, 0);                                                            \
    }                                                                           \
    _Pragma("unroll")                                                           \
    for (int c = 0; c < 2; ++c) {                                               \
      int row = c * 64 + srow;                                                  \
      const f16* g = Bt_ + (size_t)(n0 + row) * lda_ + kb + ((slot ^ (row & 7)) * 8); \
      __builtin_amdgcn_global_load_lds(                                         \
          (const __attribute__((address_space(1))) void*)g,                     \
          (__attribute__((address_space(3))) void*)(Bs + row * 64 + slot * 8),  \
          16, 0, 0);                                                            \
    }                                                                           \
    __syncthreads();                                                            \
    _Pragma("unroll")                                                           \
    for (int kh = 0; kh < 2; ++kh) {                                            \
      f16x8 af[4], bf[4];                                                       \
      _Pragma("unroll")                                                         \
      for (int m = 0; m < 4; ++m) {                                             \
        int row = wr + m * 16 + lrow;                                           \
        int sl = (g4 + 4 * kh) ^ (row & 7);                                     \
        af[m] = *(const f16x8*)(As + row * 64 + sl * 8);                        \
      }                                                                         \
      _Pragma("unroll")                                                         \
      for (int n = 0; n < 4; ++n) {                                             \
        int row = wc + n * 16 + lrow;                                           \
        int sl = (g4 + 4 * kh) ^ (row & 7);                                     \
        bf[n] = *(const f16x8*)(Bs + row * 64 + sl * 8);                        \
      }                                                                         \
      _Pragma("unroll")                                                         \
      for (int m = 0; m < 4; ++m)                                               \
        _Pragma("unroll")                                                       \
        for (int n = 0; n < 4; ++n)                                             \
          acc[m][n] = __builtin_amdgcn_mfma_f32_16x16x32_f16(af[m], bf[n], acc[m][n], 0, 0, 0); \
    }                                                                           \
  }

// ---------------- GEMM1: C = relu_f16(A @ Bt^T + bias), h1 output
__global__ __launch_bounds__(512, 4) void gemm_f16(
    const f16* __restrict__ A, const f16* __restrict__ Bt,
    const float* __restrict__ bias, f16* __restrict__ C,
    int M, int ksteps, int lda) {
  GEMM_MAIN_LOOP(A, Bt, M, ksteps, lda)

  const int ocol0 = n0 + wc + lrow;
  const int orow0 = m0 + wr + g4 * 4;
#pragma unroll
  for (int m = 0; m < 4; ++m) {
#pragma unroll
    for (int r = 0; r < 4; ++r) {
      int orow = orow0 + m * 16 + r;
      if (orow >= M) continue;
      f16* crow = C + (size_t)orow * DFC;
#pragma unroll
      for (int n = 0; n < 4; ++n) {
        int col = ocol0 + n * 16;
        float v = acc[m][n][r] + bias[col];
        crow[col] = (f16)fmaxf(v, 0.f);
      }
    }
  }
}

// ---------------- GEMM2 with fused fc3: out[m] += sum_col relu(h2)*W3[col]
__global__ __launch_bounds__(512, 4) void gemm2_fc3(
    const f16* __restrict__ A, const f16* __restrict__ Bt,
    const float* __restrict__ bias, const float* __restrict__ W3,
    float* __restrict__ out, int M, int ksteps, int lda) {
  GEMM_MAIN_LOOP(A, Bt, M, ksteps, lda)

  const int ocol0 = n0 + wc + lrow;
  const int orow0 = m0 + wr + g4 * 4;
  float b4[4], w3v[4];
#pragma unroll
  for (int n = 0; n < 4; ++n) {
    b4[n] = bias[ocol0 + n * 16];
    w3v[n] = W3[ocol0 + n * 16];
  }
#pragma unroll
  for (int m = 0; m < 4; ++m) {
#pragma unroll
    for (int r = 0; r < 4; ++r) {
      float sacc = 0.f;
#pragma unroll
      for (int n = 0; n < 4; ++n) {
        float v = fmaxf(acc[m][n][r] + b4[n], 0.f);
        sacc += v * w3v[n];
      }
      sacc += __shfl_xor(sacc, 1);
      sacc += __shfl_xor(sacc, 2);
      sacc += __shfl_xor(sacc, 4);
      sacc += __shfl_xor(sacc, 8);
      int orow = orow0 + m * 16 + r;
      if (lrow == 0 && orow < M) atomicAdd(&out[orow], sacc);
    }
  }
}

// ---------------- init out with b3 (also clears harness poison)
__global__ __launch_bounds__(256) void fill_out(
    float* __restrict__ out, const float* __restrict__ b3, int n) {
  int i = blockIdx.x * 256 + threadIdx.x;
  if (i < n) out[i] = b3[0];
}

extern "C" void kernel_launch(void* const* d_in, const int* in_sizes, int n_in,
                              void* d_out, int out_size, void* d_ws, size_t ws_size,
                              hipStream_t stream) {
  const float* feature = (const float*)d_in[0];
  const float* p       = (const float*)d_in[1];
  const float* feat    = (const float*)d_in[2];
  const float* W_fc1   = (const float*)d_in[3];
  const float* b_fc1   = (const float*)d_in[4];
  const float* W1      = (const float*)d_in[5];
  const float* b1      = (const float*)d_in[6];
  const float* W2      = (const float*)d_in[7];
  const float* b2      = (const float*)d_in[8];
  const float* W3      = (const float*)d_in[9];
  const float* b3      = (const float*)d_in[10];
  float* out = (float*)d_out;

  char* ws = (char*)d_ws;
  f16* x    = (f16*)(ws + 0);                   //  33,554,432 B
  f16* z    = (f16*)(ws + 33554432ULL);         //  87,040,000 B (40000x1088)
  f16* h1   = (f16*)(ws + 120594432ULL);        //  81,920,000 B (40000x1024)
  f16* W1t  = (f16*)(ws + 202514432ULL);        //   2,228,224 B (1024x1088)
  f16* W2t  = (f16*)(ws + 204742656ULL);        //   2,097,152 B (1024x1024)
  f16* Wc16 = (f16*)(ws + 206839808ULL);        //      65,536 B (128x256)
  f16* ft   = h1;  // 67,108,864 B <= h1 region; dead before gemm1 writes h1

  hipLaunchKernelGGL(wcast_kernel, dim3(128), dim3(256), 0, stream,
                     W_fc1, Wc16, DLOI * CDIM);
  hipLaunchKernelGGL(wtrans_kernel, dim3(32, 34), dim3(256), 0, stream,
                     W1, W1t, 1032, KP1, 1);
  hipLaunchKernelGGL(wtrans_kernel, dim3(32, 32), dim3(256), 0, stream,
                     W2, W2t, 1024, 1024, 0);
  hipLaunchKernelGGL(transpose_kernel, dim3(8192), dim3(256), 0, stream,
                     feature, ft);
  hipLaunchKernelGGL(conv_gemm, dim3(512), dim3(512), 0, stream,
                     ft, Wc16, b_fc1, x);
  hipLaunchKernelGGL(sample_kernel, dim3(10000), dim3(256), 0, stream,
                     x, p, feat, z);
  hipLaunchKernelGGL(gemm_f16, dim3(1256), dim3(512), 0, stream,
                     z, W1t, b1, h1, LROWS, KP1 / 64, KP1);
  hipLaunchKernelGGL(fill_out, dim3(157), dim3(256), 0, stream,
                     out, b3, LROWS);
  hipLaunchKernelGGL(gemm2_fc3, dim3(1256), dim3(512), 0, stream,
                     h1, W2t, b2, W3, out, LROWS, DFC / 64, DFC);
}

// Round 17
// 320.614 us; speedup vs baseline: 1.0658x; 1.0260x over previous
//
#include <hip/hip_runtime.h>

typedef _Float16 f16;
typedef __fp16 h16x2 __attribute__((ext_vector_type(2)));
typedef f16 f16x8 __attribute__((ext_vector_type(8)));
typedef float f32x4 __attribute__((ext_vector_type(4)));

#define HW    128
#define NPIX  16384      // 128*128
#define CDIM  256
#define DLOI  128
#define LROWS 40000      // B*L
#define DFC   1024
#define KP1   1088       // fc1 K (1032) padded to 17*64

// ---------------- fused transpose+conv1x1: x[b][pix][d] = feature^T @ W^T + bias
// Per block: 64 pix x 256 c. Stage f32 feature rows (coalesced float4) into
// 32KB LDS tile t16[pix][cpair] (f16x2 packed via cvt_pkrtz, transpose done in
// the WRITE index with XOR swizzle cpair^4*(pix&7)). MFMA A-frag = single
// conflict-free ds_read_b128; W read as f32 from L2 + in-reg cvt.
__global__ __launch_bounds__(256, 4) void fused_conv(
    const float* __restrict__ feature, const float* __restrict__ Wfc,
    const float* __restrict__ bfc, f16* __restrict__ x) {
  __shared__ unsigned int t16[64 * 128];     // [pix][cpair], 32 KB
  const int tid = threadIdx.x;
  const int l = tid & 63;
  const int w = tid >> 6;                    // wave 0..3 -> 32-d strip
  const int bid = blockIdx.x;                // 2048 = 256 pix-tiles x 8 batches
  const int b = bid & 7;                     // batch -> XCD pin
  const int pix0 = (bid >> 3) * 64;
  const int lrow = l & 15, g4 = l >> 4;

  const float* fb = feature + (size_t)b * CDIM * NPIX;

  // ---- stage: 8 passes; thread covers c-pair cp, pix quad px4..px4+3
  const int cpb = tid >> 4;                  // 0..15
  const int px4 = (tid & 15) * 4;
#pragma unroll
  for (int pass = 0; pass < 8; ++pass) {
    const int cp = cpb + pass * 16;          // 0..127
    const float* r0 = fb + (size_t)(2 * cp) * NPIX + pix0 + px4;
    float4 a = *(const float4*)r0;
    float4 c = *(const float4*)(r0 + NPIX);
    union { h16x2 h; unsigned int u; } v[4];
    v[0].h = __builtin_amdgcn_cvt_pkrtz(a.x, c.x);
    v[1].h = __builtin_amdgcn_cvt_pkrtz(a.y, c.y);
    v[2].h = __builtin_amdgcn_cvt_pkrtz(a.z, c.z);
    v[3].h = __builtin_amdgcn_cvt_pkrtz(a.w, c.w);
#pragma unroll
    for (int i = 0; i < 4; ++i) {
      const int pix = px4 + i;
      t16[pix * 128 + (cp ^ (4 * (pix & 7)))] = v[i].u;
    }
  }
  __syncthreads();

  // ---- compute: 8 kf steps, wave w covers d in [w*32, w*32+32)
  f32x4 acc[4][2] = {};
#pragma unroll
  for (int kf = 0; kf < 8; ++kf) {
    const int kb = kf * 32 + g4 * 8;
    f16x8 bf[2];
#pragma unroll
    for (int n = 0; n < 2; ++n) {
      const float* wp = &Wfc[(size_t)(w * 32 + n * 16 + lrow) * CDIM + kb];
      float4 w0 = *(const float4*)wp;
      float4 w1 = *(const float4*)(wp + 4);
      union { f16x8 v; h16x2 h[4]; } u;
      u.h[0] = __builtin_amdgcn_cvt_pkrtz(w0.x, w0.y);
      u.h[1] = __builtin_amdgcn_cvt_pkrtz(w0.z, w0.w);
      u.h[2] = __builtin_amdgcn_cvt_pkrtz(w1.x, w1.y);
      u.h[3] = __builtin_amdgcn_cvt_pkrtz(w1.z, w1.w);
      bf[n] = u.v;
    }
    const int cp0 = kf * 16 + g4 * 4;
#pragma unroll
    for (int m = 0; m < 4; ++m) {
      const int pix = m * 16 + lrow;
      const f16x8 af = *(const f16x8*)(t16 + pix * 128 + (cp0 ^ (4 * (pix & 7))));
#pragma unroll
      for (int n = 0; n < 2; ++n)
        acc[m][n] = __builtin_amdgcn_mfma_f32_16x16x32_f16(af, bf[n], acc[m][n], 0, 0, 0);
    }
  }

  // ---- epilogue: C/D layout col=l&15, row=(l>>4)*4+r
#pragma unroll
  for (int m = 0; m < 4; ++m) {
#pragma unroll
    for (int r = 0; r < 4; ++r) {
      const int pix = pix0 + m * 16 + g4 * 4 + r;
      f16* xr = x + ((size_t)b * NPIX + pix) * DLOI;
#pragma unroll
      for (int n = 0; n < 2; ++n) {
        const int d = w * 32 + n * 16 + lrow;
        xr[d] = (f16)(acc[m][n][r] + bfc[d]);
      }
    }
  }
}

// ---------------- sampling + bilinear + maxpool(4) + concat -> z[40000][1088] fp16
__global__ __launch_bounds__(256) void sample_kernel(
    const f16* __restrict__ x, const float* __restrict__ p,
    const float* __restrict__ feat, f16* __restrict__ z) {
  const int tid = threadIdx.x;
  const int wv = tid >> 6;
  const int lane = tid & 63;
  const int sub = lane >> 4;           // pool group within half
  const int cl = lane & 15;            // channel block (8 ch)
  const int bid = blockIdx.x;          // 0..9999
  const int b = bid & 7;               // batch -> XCD pin
  const int row = b * 5000 + (bid >> 3) * 4 + wv;

  const float4 pe = *(const float4*)&p[(size_t)row * 4]; // p0x p0y p1x p1y
  const size_t bb = (size_t)b * NPIX;
  f16* zr = z + (size_t)row * KP1;

#pragma unroll
  for (int gh = 0; gh < 2; ++gh) {
    const int g = gh * 4 + sub;        // pool group 0..7
    float acc[8];
#pragma unroll
    for (int ci = 0; ci < 8; ++ci) acc[ci] = -1e30f;
#pragma unroll
    for (int pt = 0; pt < 4; ++pt) {
      const int t = g * 4 + pt;
      const float lam = (float)t * (1.0f / 31.0f);
      const float px = pe.x * lam + pe.z * (1.f - lam) - 0.5f;
      const float py = pe.y * lam + pe.w * (1.f - lam) - 0.5f;
      const float px0 = fminf(fmaxf(floorf(px), 0.f), 127.f);
      const float py0 = fminf(fmaxf(floorf(py), 0.f), 127.f);
      const float px1 = fminf(px0 + 1.f, 127.f);
      const float py1 = fminf(py0 + 1.f, 127.f);
      const int ix0 = (int)px0, iy0 = (int)py0, ix1 = (int)px1, iy1 = (int)py1;
      const float w00 = (px1 - px) * (py1 - py);
      const float w10 = (px - px0) * (py1 - py);
      const float w01 = (px1 - px) * (py - py0);
      const float w11 = (px - px0) * (py - py0);

      const f16* r00 = x + (bb + ix0 * HW + iy0) * DLOI + cl * 8;
      const f16* r10 = x + (bb + ix1 * HW + iy0) * DLOI + cl * 8;
      const f16* r01 = x + (bb + ix0 * HW + iy1) * DLOI + cl * 8;
      const f16* r11 = x + (bb + ix1 * HW + iy1) * DLOI + cl * 8;
      f16x8 a  = *(const f16x8*)r00;
      f16x8 bq = *(const f16x8*)r10;
      f16x8 cq = *(const f16x8*)r01;
      f16x8 dq = *(const f16x8*)r11;
#pragma unroll
      for (int ci = 0; ci < 8; ++ci) {
        float m = w00 * (float)a[ci] + w10 * (float)bq[ci] +
                  w01 * (float)cq[ci] + w11 * (float)dq[ci];
        acc[ci] = fmaxf(acc[ci], m);
      }
    }
    f16x8 o;
#pragma unroll
    for (int ci = 0; ci < 8; ++ci) o[ci] = (f16)acc[ci];
    *(f16x8*)(zr + g * 128 + cl * 8) = o;
  }
  if (lane < 8) zr[1024 + lane] = (f16)feat[(size_t)row * 8 + lane];
  else if (lane < 36) *(unsigned int*)((char*)zr + 2064 + (lane - 8) * 4) = 0u;
}

// ---------------- weight transpose + fp16 + K-pad (+ optional k-permute for z layout)
__global__ __launch_bounds__(256) void wtrans_kernel(
    const float* __restrict__ W, f16* __restrict__ Wt, int K, int ldt, int permute) {
  __shared__ float t[32][33];
  const int tx = threadIdx.x & 31, ty = threadIdx.x >> 5;
#pragma unroll
  for (int i = 0; i < 4; ++i) {
    int kd = blockIdx.y * 32 + ty + i * 8;
    int ks = (permute && kd < 1024) ? ((kd & 127) * 8 + (kd >> 7)) : kd;
    int n = blockIdx.x * 32 + tx;
    t[ty + i * 8][tx] = (ks < K) ? W[(size_t)ks * DFC + n] : 0.f;
  }
  __syncthreads();
#pragma unroll
  for (int i = 0; i < 4; ++i) {
    int n = blockIdx.x * 32 + ty + i * 8;
    int k = blockIdx.y * 32 + tx;
    Wt[(size_t)n * ldt + k] = (f16)t[tx][ty + i * 8];
  }
}

// ================= 256x128-tile GEMM main loop, 8 waves (512 thr).
// FROZEN (r12): conflict-free 16x16x32, 2-barrier K-loop, 48KB LDS,
// 3-4 blocks/CU, ~860 TF (2-barrier-family ceiling).
#define GEMM_MAIN_LOOP(A_, Bt_, M_, ksteps_, lda_)                              \
  __shared__ f16 As[256 * 64];                                                  \
  __shared__ f16 Bs[128 * 64];                                                  \
  const int tid = threadIdx.x;                                                  \
  const int l = tid & 63;                                                       \
  const int w = tid >> 6;                                                       \
  const int nwg = gridDim.x;            /* 1256 = 8*157 */                      \
  const int s = (blockIdx.x & 7) * (nwg >> 3) + (blockIdx.x >> 3);              \
  const int m0 = (s >> 3) * 256;                                                \
  const int n0 = (s & 7) * 128;                                                 \
  const int wr = (w >> 1) * 64, wc = (w & 1) * 64;                              \
  const int srow = tid >> 3;            /* 0..63 */                             \
  const int slot = tid & 7;                                                     \
  const int lrow = l & 15, g4 = l >> 4;                                         \
  f32x4 acc[4][4] = {};                                                         \
  for (int kt = 0; kt < ksteps_; ++kt) {                                        \
    const int kb = kt * 64;                                                     \
    __syncthreads();                                                            \
    _Pragma("unroll")                                                           \
    for (int c = 0; c < 4; ++c) {                                               \
      int row = c * 64 + srow;                                                  \
      int arow = m0 + row; if (arow >= M_) arow = M_ - 1;                       \
      const f16* g = A_ + (size_t)arow * lda_ + kb + ((slot ^ (row & 7)) * 8);  \
      __builtin_amdgcn_global_load_lds(                                         \
          (const __attribute__((address_space(1))) void*)g,                     \
          (__attribute__((address_space(3))) void*)(As + row * 64 + slot * 8),  \
          16, 0, 0);                                                            \
    }                                                                           \
    _Pragma("unroll")                                                           \
    for (int c = 0; c < 2; ++c) {                                               \
      int row = c * 64 + srow;                                                  \
      const f16* g = Bt_ + (size_t)(n0 + row) * lda_ + kb + ((slot ^ (row & 7)) * 8); \
      __builtin_amdgcn_global_load_lds(                                         \
          (const __attribute__((address_space(1))) void*)g,                     \
          (__attribute__((address_space(3))) void*)(Bs + row * 64 + slot * 8),  \
          16, 0, 0);                                                            \
    }                                                                           \
    __syncthreads();                                                            \
    _Pragma("unroll")                                                           \
    for (int kh = 0; kh < 2; ++kh) {                                            \
      f16x8 af[4], bf[4];                                                       \
      _Pragma("unroll")                                                         \
      for (int m = 0; m < 4; ++m) {                                             \
        int row = wr + m * 16 + lrow;                                           \
        int sl = (g4 + 4 * kh) ^ (row & 7);                                     \
        af[m] = *(const f16x8*)(As + row * 64 + sl * 8);                        \
      }                                                                         \
      _Pragma("unroll")                                                         \
      for (int n = 0; n < 4; ++n) {                                             \
        int row = wc + n * 16 + lrow;                                           \
        int sl = (g4 + 4 * kh) ^ (row & 7);                                     \
        bf[n] = *(const f16x8*)(Bs + row * 64 + sl * 8);                        \
      }                                                                         \
      _Pragma("unroll")                                                         \
      for (int m = 0; m < 4; ++m)                                               \
        _Pragma("unroll")                                                       \
        for (int n = 0; n < 4; ++n)                                             \
          acc[m][n] = __builtin_amdgcn_mfma_f32_16x16x32_f16(af[m], bf[n], acc[m][n], 0, 0, 0); \
    }                                                                           \
  }

// ---------------- GEMM1: C = relu_f16(A @ Bt^T + bias), h1 output
__global__ __launch_bounds__(512, 4) void gemm_f16(
    const f16* __restrict__ A, const f16* __restrict__ Bt,
    const float* __restrict__ bias, f16* __restrict__ C,
    int M, int ksteps, int lda) {
  GEMM_MAIN_LOOP(A, Bt, M, ksteps, lda)

  const int ocol0 = n0 + wc + lrow;
  const int orow0 = m0 + wr + g4 * 4;
#pragma unroll
  for (int m = 0; m < 4; ++m) {
#pragma unroll
    for (int r = 0; r < 4; ++r) {
      int orow = orow0 + m * 16 + r;
      if (orow >= M) continue;
      f16* crow = C + (size_t)orow * DFC;
#pragma unroll
      for (int n = 0; n < 4; ++n) {
        int col = ocol0 + n * 16;
        float v = acc[m][n][r] + bias[col];
        crow[col] = (f16)fmaxf(v, 0.f);
      }
    }
  }
}

// ---------------- GEMM2 with fused fc3: out[m] += sum_col relu(h2)*W3[col]
__global__ __launch_bounds__(512, 4) void gemm2_fc3(
    const f16* __restrict__ A, const f16* __restrict__ Bt,
    const float* __restrict__ bias, const float* __restrict__ W3,
    float* __restrict__ out, int M, int ksteps, int lda) {
  GEMM_MAIN_LOOP(A, Bt, M, ksteps, lda)

  const int ocol0 = n0 + wc + lrow;
  const int orow0 = m0 + wr + g4 * 4;
  float b4[4], w3v[4];
#pragma unroll
  for (int n = 0; n < 4; ++n) {
    b4[n] = bias[ocol0 + n * 16];
    w3v[n] = W3[ocol0 + n * 16];
  }
#pragma unroll
  for (int m = 0; m < 4; ++m) {
#pragma unroll
    for (int r = 0; r < 4; ++r) {
      float sacc = 0.f;
#pragma unroll
      for (int n = 0; n < 4; ++n) {
        float v = fmaxf(acc[m][n][r] + b4[n], 0.f);
        sacc += v * w3v[n];
      }
      sacc += __shfl_xor(sacc, 1);
      sacc += __shfl_xor(sacc, 2);
      sacc += __shfl_xor(sacc, 4);
      sacc += __shfl_xor(sacc, 8);
      int orow = orow0 + m * 16 + r;
      if (lrow == 0 && orow < M) atomicAdd(&out[orow], sacc);
    }
  }
}

// ---------------- init out with b3 (also clears harness poison)
__global__ __launch_bounds__(256) void fill_out(
    float* __restrict__ out, const float* __restrict__ b3, int n) {
  int i = blockIdx.x * 256 + threadIdx.x;
  if (i < n) out[i] = b3[0];
}

extern "C" void kernel_launch(void* const* d_in, const int* in_sizes, int n_in,
                              void* d_out, int out_size, void* d_ws, size_t ws_size,
                              hipStream_t stream) {
  const float* feature = (const float*)d_in[0];
  const float* p       = (const float*)d_in[1];
  const float* feat    = (const float*)d_in[2];
  const float* W_fc1   = (const float*)d_in[3];
  const float* b_fc1   = (const float*)d_in[4];
  const float* W1      = (const float*)d_in[5];
  const float* b1      = (const float*)d_in[6];
  const float* W2      = (const float*)d_in[7];
  const float* b2      = (const float*)d_in[8];
  const float* W3      = (const float*)d_in[9];
  const float* b3      = (const float*)d_in[10];
  float* out = (float*)d_out;

  char* ws = (char*)d_ws;
  f16* x    = (f16*)(ws + 0);                   //  33,554,432 B
  f16* z    = (f16*)(ws + 33554432ULL);         //  87,040,000 B (40000x1088)
  f16* h1   = (f16*)(ws + 120594432ULL);        //  81,920,000 B (40000x1024)
  f16* W1t  = (f16*)(ws + 202514432ULL);        //   2,228,224 B (1024x1088)
  f16* W2t  = (f16*)(ws + 204742656ULL);        //   2,097,152 B (1024x1024)

  hipLaunchKernelGGL(wtrans_kernel, dim3(32, 34), dim3(256), 0, stream,
                     W1, W1t, 1032, KP1, 1);
  hipLaunchKernelGGL(wtrans_kernel, dim3(32, 32), dim3(256), 0, stream,
                     W2, W2t, 1024, 1024, 0);
  // 2048 blocks: batch = bid&7 (XCD pin), pix-tile = bid>>3
  hipLaunchKernelGGL(fused_conv, dim3(2048), dim3(256), 0, stream,
                     feature, W_fc1, b_fc1, x);
  hipLaunchKernelGGL(sample_kernel, dim3(10000), dim3(256), 0, stream,
                     x, p, feat, z);
  hipLaunchKernelGGL(gemm_f16, dim3(1256), dim3(512), 0, stream,
                     z, W1t, b1, h1, LROWS, KP1 / 64, KP1);
  hipLaunchKernelGGL(fill_out, dim3(157), dim3(256), 0, stream,
                     out, b3, LROWS);
  hipLaunchKernelGGL(gemm2_fc3, dim3(1256), dim3(512), 0, stream,
                     h1, W2t, b2, W3, out, LROWS, DFC / 64, DFC);
}

// Round 18
// 320.053 us; speedup vs baseline: 1.0677x; 1.0018x over previous
//
#include <hip/hip_runtime.h>

typedef _Float16 f16;
typedef __fp16 h16x2 __attribute__((ext_vector_type(2)));
typedef f16 f16x8 __attribute__((ext_vector_type(8)));
typedef float f32x4 __attribute__((ext_vector_type(4)));

#define HW    128
#define NPIX  16384      // 128*128
#define CDIM  256
#define DLOI  128
#define LROWS 40000      // B*L
#define DFC   1024
#define KZ    1032       // z row stride (true K; W1t zero-padded to 1088 covers tail)
#define KP1   1088       // W1t row stride (17*64), zeros for k >= 1032

// ---------------- mega prep kernel: fused conv (blocks 0..2047) +
// W1 transpose (1088) + W2 transpose (1024) + out fill (157). One launch;
// cheap memory-bound prep blocks backfill CUs as conv blocks retire.
__device__ __forceinline__ void wtrans_body(
    const float* __restrict__ W, f16* __restrict__ Wt, int K, int ldt,
    int permute, int bx, int by, int tid, float (*t)[33]) {
  const int tx = tid & 31, ty = tid >> 5;
#pragma unroll
  for (int i = 0; i < 4; ++i) {
    int kd = by * 32 + ty + i * 8;
    int ks = (permute && kd < 1024) ? ((kd & 127) * 8 + (kd >> 7)) : kd;
    int n = bx * 32 + tx;
    t[ty + i * 8][tx] = (ks < K) ? W[(size_t)ks * DFC + n] : 0.f;
  }
  __syncthreads();
#pragma unroll
  for (int i = 0; i < 4; ++i) {
    int n = bx * 32 + ty + i * 8;
    int k = by * 32 + tx;
    Wt[(size_t)n * ldt + k] = (f16)t[tx][ty + i * 8];
  }
}

__global__ __launch_bounds__(256, 4) void conv_prep(
    const float* __restrict__ feature, const float* __restrict__ Wfc,
    const float* __restrict__ bfc, f16* __restrict__ x,
    const float* __restrict__ W1, f16* __restrict__ W1t,
    const float* __restrict__ W2, f16* __restrict__ W2t,
    float* __restrict__ out, const float* __restrict__ b3) {
  __shared__ unsigned int t16[64 * 128];     // conv tile, 32 KB
  __shared__ float tt[32][33];               // wtrans tile
  const int tid = threadIdx.x;
  const int bid = blockIdx.x;

  if (bid >= 2048) {
    if (bid < 3136) {        // W1 transpose+permute: 32 x 34 tiles
      const int lo = bid - 2048;
      wtrans_body(W1, W1t, 1032, KP1, 1, lo & 31, lo >> 5, tid, tt);
    } else if (bid < 4160) { // W2 transpose: 32 x 32 tiles
      const int lo = bid - 3136;
      wtrans_body(W2, W2t, 1024, 1024, 0, lo & 31, lo >> 5, tid, tt);
    } else {                 // fill out with b3
      const int i = (bid - 4160) * 256 + tid;
      if (i < LROWS) out[i] = b3[0];
    }
    return;
  }

  // ----- fused transpose+conv1x1 (identical to r17's verified body)
  const int l = tid & 63;
  const int w = tid >> 6;                    // wave 0..3 -> 32-d strip
  const int b = bid & 7;                     // batch -> XCD pin
  const int pix0 = (bid >> 3) * 64;
  const int lrow = l & 15, g4 = l >> 4;

  const float* fb = feature + (size_t)b * CDIM * NPIX;

  const int cpb = tid >> 4;                  // 0..15
  const int px4 = (tid & 15) * 4;
#pragma unroll
  for (int pass = 0; pass < 8; ++pass) {
    const int cp = cpb + pass * 16;          // 0..127
    const float* r0 = fb + (size_t)(2 * cp) * NPIX + pix0 + px4;
    float4 a = *(const float4*)r0;
    float4 c = *(const float4*)(r0 + NPIX);
    union { h16x2 h; unsigned int u; } v[4];
    v[0].h = __builtin_amdgcn_cvt_pkrtz(a.x, c.x);
    v[1].h = __builtin_amdgcn_cvt_pkrtz(a.y, c.y);
    v[2].h = __builtin_amdgcn_cvt_pkrtz(a.z, c.z);
    v[3].h = __builtin_amdgcn_cvt_pkrtz(a.w, c.w);
#pragma unroll
    for (int i = 0; i < 4; ++i) {
      const int pix = px4 + i;
      t16[pix * 128 + (cp ^ (4 * (pix & 7)))] = v[i].u;
    }
  }
  __syncthreads();

  f32x4 acc[4][2] = {};
#pragma unroll
  for (int kf = 0; kf < 8; ++kf) {
    const int kb = kf * 32 + g4 * 8;
    f16x8 bf[2];
#pragma unroll
    for (int n = 0; n < 2; ++n) {
      const float* wp = &Wfc[(size_t)(w * 32 + n * 16 + lrow) * CDIM + kb];
      float4 w0 = *(const float4*)wp;
      float4 w1 = *(const float4*)(wp + 4);
      union { f16x8 v; h16x2 h[4]; } u;
      u.h[0] = __builtin_amdgcn_cvt_pkrtz(w0.x, w0.y);
      u.h[1] = __builtin_amdgcn_cvt_pkrtz(w0.z, w0.w);
      u.h[2] = __builtin_amdgcn_cvt_pkrtz(w1.x, w1.y);
      u.h[3] = __builtin_amdgcn_cvt_pkrtz(w1.z, w1.w);
      bf[n] = u.v;
    }
    const int cp0 = kf * 16 + g4 * 4;
#pragma unroll
    for (int m = 0; m < 4; ++m) {
      const int pix = m * 16 + lrow;
      const f16x8 af = *(const f16x8*)(t16 + pix * 128 + (cp0 ^ (4 * (pix & 7))));
#pragma unroll
      for (int n = 0; n < 2; ++n)
        acc[m][n] = __builtin_amdgcn_mfma_f32_16x16x32_f16(af, bf[n], acc[m][n], 0, 0, 0);
    }
  }

#pragma unroll
  for (int m = 0; m < 4; ++m) {
#pragma unroll
    for (int r = 0; r < 4; ++r) {
      const int pix = pix0 + m * 16 + g4 * 4 + r;
      f16* xr = x + ((size_t)b * NPIX + pix) * DLOI;
#pragma unroll
      for (int n = 0; n < 2; ++n) {
        const int d = w * 32 + n * 16 + lrow;
        xr[d] = (f16)(acc[m][n][r] + bfc[d]);
      }
    }
  }
}

// ---------------- sampling + bilinear + maxpool(4) + concat -> z[40000][1032] fp16
__global__ __launch_bounds__(256) void sample_kernel(
    const f16* __restrict__ x, const float* __restrict__ p,
    const float* __restrict__ feat, f16* __restrict__ z) {
  const int tid = threadIdx.x;
  const int wv = tid >> 6;
  const int lane = tid & 63;
  const int sub = lane >> 4;           // pool group within half
  const int cl = lane & 15;            // channel block (8 ch)
  const int bid = blockIdx.x;          // 0..9999
  const int b = bid & 7;               // batch -> XCD pin
  const int row = b * 5000 + (bid >> 3) * 4 + wv;

  const float4 pe = *(const float4*)&p[(size_t)row * 4]; // p0x p0y p1x p1y
  const size_t bb = (size_t)b * NPIX;
  f16* zr = z + (size_t)row * KZ;

#pragma unroll
  for (int gh = 0; gh < 2; ++gh) {
    const int g = gh * 4 + sub;        // pool group 0..7
    float acc[8];
#pragma unroll
    for (int ci = 0; ci < 8; ++ci) acc[ci] = -1e30f;
#pragma unroll
    for (int pt = 0; pt < 4; ++pt) {
      const int t = g * 4 + pt;
      const float lam = (float)t * (1.0f / 31.0f);
      const float px = pe.x * lam + pe.z * (1.f - lam) - 0.5f;
      const float py = pe.y * lam + pe.w * (1.f - lam) - 0.5f;
      const float px0 = fminf(fmaxf(floorf(px), 0.f), 127.f);
      const float py0 = fminf(fmaxf(floorf(py), 0.f), 127.f);
      const float px1 = fminf(px0 + 1.f, 127.f);
      const float py1 = fminf(py0 + 1.f, 127.f);
      const int ix0 = (int)px0, iy0 = (int)py0, ix1 = (int)px1, iy1 = (int)py1;
      const float w00 = (px1 - px) * (py1 - py);
      const float w10 = (px - px0) * (py1 - py);
      const float w01 = (px1 - px) * (py - py0);
      const float w11 = (px - px0) * (py - py0);

      const f16* r00 = x + (bb + ix0 * HW + iy0) * DLOI + cl * 8;
      const f16* r10 = x + (bb + ix1 * HW + iy0) * DLOI + cl * 8;
      const f16* r01 = x + (bb + ix0 * HW + iy1) * DLOI + cl * 8;
      const f16* r11 = x + (bb + ix1 * HW + iy1) * DLOI + cl * 8;
      f16x8 a  = *(const f16x8*)r00;
      f16x8 bq = *(const f16x8*)r10;
      f16x8 cq = *(const f16x8*)r01;
      f16x8 dq = *(const f16x8*)r11;
#pragma unroll
      for (int ci = 0; ci < 8; ++ci) {
        float m = w00 * (float)a[ci] + w10 * (float)bq[ci] +
                  w01 * (float)cq[ci] + w11 * (float)dq[ci];
        acc[ci] = fmaxf(acc[ci], m);
      }
    }
    f16x8 o;
#pragma unroll
    for (int ci = 0; ci < 8; ++ci) o[ci] = (f16)acc[ci];
    *(f16x8*)(zr + g * 128 + cl * 8) = o;
  }
  if (lane < 8) zr[1024 + lane] = (f16)feat[(size_t)row * 8 + lane];
}

// ================= 256x128-tile GEMM main loop, 8 waves (512 thr).
// FROZEN (r12): conflict-free 16x16x32, 2-barrier K-loop, 48KB LDS,
// 3 blocks/CU, ~900 TF (2-barrier-family ceiling). Now with separate
// lda/ldb: A may carry garbage in k>=true-K (B stores zeros there).
#define GEMM_MAIN_LOOP(A_, Bt_, M_, ksteps_, lda_, ldb_)                        \
  __shared__ f16 As[256 * 64];                                                  \
  __shared__ f16 Bs[128 * 64];                                                  \
  const int tid = threadIdx.x;                                                  \
  const int l = tid & 63;                                                       \
  const int w = tid >> 6;                                                       \
  const int nwg = gridDim.x;            /* 1256 = 8*157 */                      \
  const int s = (blockIdx.x & 7) * (nwg >> 3) + (blockIdx.x >> 3);              \
  const int m0 = (s >> 3) * 256;                                                \
  const int n0 = (s & 7) * 128;                                                 \
  const int wr = (w >> 1) * 64, wc = (w & 1) * 64;                              \
  const int srow = tid >> 3;            /* 0..63 */                             \
  const int slot = tid & 7;                                                     \
  const int lrow = l & 15, g4 = l >> 4;                                         \
  f32x4 acc[4][4] = {};                                                         \
  for (int kt = 0; kt < ksteps_; ++kt) {                                        \
    const int kb = kt * 64;                                                     \
    __syncthreads();                                                            \
    _Pragma("unroll")                                                           \
    for (int c = 0; c < 4; ++c) {                                               \
      int row = c * 64 + srow;                                                  \
      int arow = m0 + row; if (arow >= M_) arow = M_ - 1;                       \
      const f16* g = A_ + (size_t)arow * lda_ + kb + ((slot ^ (row & 7)) * 8);  \
      __builtin_amdgcn_global_load_lds(                                         \
          (const __attribute__((address_space(1))) void*)g,                     \
          (__attribute__((address_space(3))) void*)(As + row * 64 + slot * 8),  \
          16, 0, 0);                                                            \
    }                                                                           \
    _Pragma("unroll")                                                           \
    for (int c = 0; c < 2; ++c) {                                               \
      int row = c * 64 + srow;                                                  \
      const f16* g = Bt_ + (size_t)(n0 + row) * ldb_ + kb + ((slot ^ (row & 7)) * 8); \
      __builtin_amdgcn_global_load_lds(                                         \
          (const __attribute__((address_space(1))) void*)g,                     \
          (__attribute__((address_space(3))) void*)(Bs + row * 64 + slot * 8),  \
          16, 0, 0);                                                            \
    }                                                                           \
    __syncthreads();                                                            \
    _Pragma("unroll")                                                           \
    for (int kh = 0; kh < 2; ++kh) {                                            \
      f16x8 af[4], bf[4];                                                       \
      _Pragma("unroll")                                                         \
      for (int m = 0; m < 4; ++m) {                                             \
        int row = wr + m * 16 + lrow;                                           \
        int sl = (g4 + 4 * kh) ^ (row & 7);                                     \
        af[m] = *(const f16x8*)(As + row * 64 + sl * 8);                        \
      }                                                                         \
      _Pragma("unroll")                                                         \
      for (int n = 0; n < 4; ++n) {                                             \
        int row = wc + n * 16 + lrow;                                           \
        int sl = (g4 + 4 * kh) ^ (row & 7);                                     \
        bf[n] = *(const f16x8*)(Bs + row * 64 + sl * 8);                        \
      }                                                                         \
      _Pragma("unroll")                                                         \
      for (int m = 0; m < 4; ++m)                                               \
        _Pragma("unroll")                                                       \
        for (int n = 0; n < 4; ++n)                                             \
          acc[m][n] = __builtin_amdgcn_mfma_f32_16x16x32_f16(af[m], bf[n], acc[m][n], 0, 0, 0); \
    }                                                                           \
  }

// ---------------- GEMM1: C = relu_f16(A @ Bt^T + bias), h1 output
__global__ __launch_bounds__(512, 4) void gemm_f16(
    const f16* __restrict__ A, const f16* __restrict__ Bt,
    const float* __restrict__ bias, f16* __restrict__ C,
    int M, int ksteps, int lda, int ldb) {
  GEMM_MAIN_LOOP(A, Bt, M, ksteps, lda, ldb)

  const int ocol0 = n0 + wc + lrow;
  const int orow0 = m0 + wr + g4 * 4;
#pragma unroll
  for (int m = 0; m < 4; ++m) {
#pragma unroll
    for (int r = 0; r < 4; ++r) {
      int orow = orow0 + m * 16 + r;
      if (orow >= M) continue;
      f16* crow = C + (size_t)orow * DFC;
#pragma unroll
      for (int n = 0; n < 4; ++n) {
        int col = ocol0 + n * 16;
        float v = acc[m][n][r] + bias[col];
        crow[col] = (f16)fmaxf(v, 0.f);
      }
    }
  }
}

// ---------------- GEMM2 with fused fc3: out[m] += sum_col relu(h2)*W3[col]
__global__ __launch_bounds__(512, 4) void gemm2_fc3(
    const f16* __restrict__ A, const f16* __restrict__ Bt,
    const float* __restrict__ bias, const float* __restrict__ W3,
    float* __restrict__ out, int M, int ksteps, int lda, int ldb) {
  GEMM_MAIN_LOOP(A, Bt, M, ksteps, lda, ldb)

  const int ocol0 = n0 + wc + lrow;
  const int orow0 = m0 + wr + g4 * 4;
  float b4[4], w3v[4];
#pragma unroll
  for (int n = 0; n < 4; ++n) {
    b4[n] = bias[ocol0 + n * 16];
    w3v[n] = W3[ocol0 + n * 16];
  }
#pragma unroll
  for (int m = 0; m < 4; ++m) {
#pragma unroll
    for (int r = 0; r < 4; ++r) {
      float sacc = 0.f;
#pragma unroll
      for (int n = 0; n < 4; ++n) {
        float v = fmaxf(acc[m][n][r] + b4[n], 0.f);
        sacc += v * w3v[n];
      }
      sacc += __shfl_xor(sacc, 1);
      sacc += __shfl_xor(sacc, 2);
      sacc += __shfl_xor(sacc, 4);
      sacc += __shfl_xor(sacc, 8);
      int orow = orow0 + m * 16 + r;
      if (lrow == 0 && orow < M) atomicAdd(&out[orow], sacc);
    }
  }
}

extern "C" void kernel_launch(void* const* d_in, const int* in_sizes, int n_in,
                              void* d_out, int out_size, void* d_ws, size_t ws_size,
                              hipStream_t stream) {
  const float* feature = (const float*)d_in[0];
  const float* p       = (const float*)d_in[1];
  const float* feat    = (const float*)d_in[2];
  const float* W_fc1   = (const float*)d_in[3];
  const float* b_fc1   = (const float*)d_in[4];
  const float* W1      = (const float*)d_in[5];
  const float* b1      = (const float*)d_in[6];
  const float* W2      = (const float*)d_in[7];
  const float* b2      = (const float*)d_in[8];
  const float* W3      = (const float*)d_in[9];
  const float* b3      = (const float*)d_in[10];
  float* out = (float*)d_out;

  char* ws = (char*)d_ws;
  f16* x    = (f16*)(ws + 0);                   //  33,554,432 B
  f16* z    = (f16*)(ws + 33554432ULL);         //  82,560,000 B (40000x1032); ends 116,114,432 (<h1, 4.4MB guard)
  f16* h1   = (f16*)(ws + 120594432ULL);        //  81,920,000 B (40000x1024)
  f16* W1t  = (f16*)(ws + 202514432ULL);        //   2,228,224 B (1024x1088, zeros k>=1032)
  f16* W2t  = (f16*)(ws + 204742656ULL);        //   2,097,152 B (1024x1024)

  // one wide launch: conv (2048) + W1t (1088) + W2t (1024) + fill (157)
  hipLaunchKernelGGL(conv_prep, dim3(4317), dim3(256), 0, stream,
                     feature, W_fc1, b_fc1, x, W1, W1t, W2, W2t, out, b3);
  hipLaunchKernelGGL(sample_kernel, dim3(10000), dim3(256), 0, stream,
                     x, p, feat, z);
  hipLaunchKernelGGL(gemm_f16, dim3(1256), dim3(512), 0, stream,
                     z, W1t, b1, h1, LROWS, KP1 / 64, KZ, KP1);
  hipLaunchKernelGGL(gemm2_fc3, dim3(1256), dim3(512), 0, stream,
                     h1, W2t, b2, W3, out, LROWS, DFC / 64, DFC, DFC);
}

// Round 19
// 310.284 us; speedup vs baseline: 1.1013x; 1.0315x over previous
//
#include <hip/hip_runtime.h>

typedef _Float16 f16;
typedef __fp16 h16x2 __attribute__((ext_vector_type(2)));
typedef f16 f16x8 __attribute__((ext_vector_type(8)));
typedef float f32x4 __attribute__((ext_vector_type(4)));

#define HW    128
#define NPIX  16384      // 128*128
#define CDIM  256
#define DLOI  128
#define LROWS 40000      // B*L
#define DFC   1024
#define KP1   1088       // z / W1t row stride (17*64); cols 1032..1087 zero

// ---------------- mega prep kernel: fused conv (blocks 0..2047) +
// W1 transpose (1088) + W2 transpose (1024) + out fill (157). One launch;
// cheap memory-bound prep blocks backfill CUs as conv blocks retire.
__device__ __forceinline__ void wtrans_body(
    const float* __restrict__ W, f16* __restrict__ Wt, int K, int ldt,
    int permute, int bx, int by, int tid, float (*t)[33]) {
  const int tx = tid & 31, ty = tid >> 5;
#pragma unroll
  for (int i = 0; i < 4; ++i) {
    int kd = by * 32 + ty + i * 8;
    int ks = (permute && kd < 1024) ? ((kd & 127) * 8 + (kd >> 7)) : kd;
    int n = bx * 32 + tx;
    t[ty + i * 8][tx] = (ks < K) ? W[(size_t)ks * DFC + n] : 0.f;
  }
  __syncthreads();
#pragma unroll
  for (int i = 0; i < 4; ++i) {
    int n = bx * 32 + ty + i * 8;
    int k = by * 32 + tx;
    Wt[(size_t)n * ldt + k] = (f16)t[tx][ty + i * 8];
  }
}

__global__ __launch_bounds__(256, 4) void conv_prep(
    const float* __restrict__ feature, const float* __restrict__ Wfc,
    const float* __restrict__ bfc, f16* __restrict__ x,
    const float* __restrict__ W1, f16* __restrict__ W1t,
    const float* __restrict__ W2, f16* __restrict__ W2t,
    float* __restrict__ out, const float* __restrict__ b3) {
  __shared__ unsigned int t16[64 * 128];     // conv tile, 32 KB
  __shared__ float tt[32][33];               // wtrans tile
  const int tid = threadIdx.x;
  const int bid = blockIdx.x;

  if (bid >= 2048) {
    if (bid < 3136) {        // W1 transpose+permute: 32 x 34 tiles
      const int lo = bid - 2048;
      wtrans_body(W1, W1t, 1032, KP1, 1, lo & 31, lo >> 5, tid, tt);
    } else if (bid < 4160) { // W2 transpose: 32 x 32 tiles
      const int lo = bid - 3136;
      wtrans_body(W2, W2t, 1024, 1024, 0, lo & 31, lo >> 5, tid, tt);
    } else {                 // fill out with b3
      const int i = (bid - 4160) * 256 + tid;
      if (i < LROWS) out[i] = b3[0];
    }
    return;
  }

  // ----- fused transpose+conv1x1 (r17's verified body)
  const int l = tid & 63;
  const int w = tid >> 6;                    // wave 0..3 -> 32-d strip
  const int b = bid & 7;                     // batch -> XCD pin
  const int pix0 = (bid >> 3) * 64;
  const int lrow = l & 15, g4 = l >> 4;

  const float* fb = feature + (size_t)b * CDIM * NPIX;

  const int cpb = tid >> 4;                  // 0..15
  const int px4 = (tid & 15) * 4;
#pragma unroll
  for (int pass = 0; pass < 8; ++pass) {
    const int cp = cpb + pass * 16;          // 0..127
    const float* r0 = fb + (size_t)(2 * cp) * NPIX + pix0 + px4;
    float4 a = *(const float4*)r0;
    float4 c = *(const float4*)(r0 + NPIX);
    union { h16x2 h; unsigned int u; } v[4];
    v[0].h = __builtin_amdgcn_cvt_pkrtz(a.x, c.x);
    v[1].h = __builtin_amdgcn_cvt_pkrtz(a.y, c.y);
    v[2].h = __builtin_amdgcn_cvt_pkrtz(a.z, c.z);
    v[3].h = __builtin_amdgcn_cvt_pkrtz(a.w, c.w);
#pragma unroll
    for (int i = 0; i < 4; ++i) {
      const int pix = px4 + i;
      t16[pix * 128 + (cp ^ (4 * (pix & 7)))] = v[i].u;
    }
  }
  __syncthreads();

  f32x4 acc[4][2] = {};
#pragma unroll
  for (int kf = 0; kf < 8; ++kf) {
    const int kb = kf * 32 + g4 * 8;
    f16x8 bf[2];
#pragma unroll
    for (int n = 0; n < 2; ++n) {
      const float* wp = &Wfc[(size_t)(w * 32 + n * 16 + lrow) * CDIM + kb];
      float4 w0 = *(const float4*)wp;
      float4 w1 = *(const float4*)(wp + 4);
      union { f16x8 v; h16x2 h[4]; } u;
      u.h[0] = __builtin_amdgcn_cvt_pkrtz(w0.x, w0.y);
      u.h[1] = __builtin_amdgcn_cvt_pkrtz(w0.z, w0.w);
      u.h[2] = __builtin_amdgcn_cvt_pkrtz(w1.x, w1.y);
      u.h[3] = __builtin_amdgcn_cvt_pkrtz(w1.z, w1.w);
      bf[n] = u.v;
    }
    const int cp0 = kf * 16 + g4 * 4;
#pragma unroll
    for (int m = 0; m < 4; ++m) {
      const int pix = m * 16 + lrow;
      const f16x8 af = *(const f16x8*)(t16 + pix * 128 + (cp0 ^ (4 * (pix & 7))));
#pragma unroll
      for (int n = 0; n < 2; ++n)
        acc[m][n] = __builtin_amdgcn_mfma_f32_16x16x32_f16(af, bf[n], acc[m][n], 0, 0, 0);
    }
  }

#pragma unroll
  for (int m = 0; m < 4; ++m) {
#pragma unroll
    for (int r = 0; r < 4; ++r) {
      const int pix = pix0 + m * 16 + g4 * 4 + r;
      f16* xr = x + ((size_t)b * NPIX + pix) * DLOI;
#pragma unroll
      for (int n = 0; n < 2; ++n) {
        const int d = w * 32 + n * 16 + lrow;
        xr[d] = (f16)(acc[m][n][r] + bfc[d]);
      }
    }
  }
}

// ---------------- sampling + bilinear + maxpool(4) + concat -> z[40000][1088] fp16
__global__ __launch_bounds__(256) void sample_kernel(
    const f16* __restrict__ x, const float* __restrict__ p,
    const float* __restrict__ feat, f16* __restrict__ z) {
  const int tid = threadIdx.x;
  const int wv = tid >> 6;
  const int lane = tid & 63;
  const int sub = lane >> 4;           // pool group within half
  const int cl = lane & 15;            // channel block (8 ch)
  const int bid = blockIdx.x;          // 0..9999
  const int b = bid & 7;               // batch -> XCD pin
  const int row = b * 5000 + (bid >> 3) * 4 + wv;

  const float4 pe = *(const float4*)&p[(size_t)row * 4]; // p0x p0y p1x p1y
  const size_t bb = (size_t)b * NPIX;
  f16* zr = z + (size_t)row * KP1;

#pragma unroll
  for (int gh = 0; gh < 2; ++gh) {
    const int g = gh * 4 + sub;        // pool group 0..7
    float acc[8];
#pragma unroll
    for (int ci = 0; ci < 8; ++ci) acc[ci] = -1e30f;
#pragma unroll
    for (int pt = 0; pt < 4; ++pt) {
      const int t = g * 4 + pt;
      const float lam = (float)t * (1.0f / 31.0f);
      const float px = pe.x * lam + pe.z * (1.f - lam) - 0.5f;
      const float py = pe.y * lam + pe.w * (1.f - lam) - 0.5f;
      const float px0 = fminf(fmaxf(floorf(px), 0.f), 127.f);
      const float py0 = fminf(fmaxf(floorf(py), 0.f), 127.f);
      const float px1 = fminf(px0 + 1.f, 127.f);
      const float py1 = fminf(py0 + 1.f, 127.f);
      const int ix0 = (int)px0, iy0 = (int)py0, ix1 = (int)px1, iy1 = (int)py1;
      const float w00 = (px1 - px) * (py1 - py);
      const float w10 = (px - px0) * (py1 - py);
      const float w01 = (px1 - px) * (py - py0);
      const float w11 = (px - px0) * (py - py0);

      const f16* r00 = x + (bb + ix0 * HW + iy0) * DLOI + cl * 8;
      const f16* r10 = x + (bb + ix1 * HW + iy0) * DLOI + cl * 8;
      const f16* r01 = x + (bb + ix0 * HW + iy1) * DLOI + cl * 8;
      const f16* r11 = x + (bb + ix1 * HW + iy1) * DLOI + cl * 8;
      f16x8 a  = *(const f16x8*)r00;
      f16x8 bq = *(const f16x8*)r10;
      f16x8 cq = *(const f16x8*)r01;
      f16x8 dq = *(const f16x8*)r11;
#pragma unroll
      for (int ci = 0; ci < 8; ++ci) {
        float m = w00 * (float)a[ci] + w10 * (float)bq[ci] +
                  w01 * (float)cq[ci] + w11 * (float)dq[ci];
        acc[ci] = fmaxf(acc[ci], m);
      }
    }
    f16x8 o;
#pragma unroll
    for (int ci = 0; ci < 8; ++ci) o[ci] = (f16)acc[ci];
    *(f16x8*)(zr + g * 128 + cl * 8) = o;
  }
  if (lane < 8) zr[1024 + lane] = (f16)feat[(size_t)row * 8 + lane];
  else if (lane < 36) *(unsigned int*)((char*)zr + 2064 + (lane - 8) * 4) = 0u;
}

// ================= 256x128-tile GEMM main loop, 8 waves (512 thr).
// FROZEN (r12): conflict-free 16x16x32, 2-barrier K-loop, 48KB LDS,
// 3 blocks/CU, ~900 TF (2-barrier-family ceiling). 128B-aligned strides only
// (r18 lesson: unaligned A-row stride costs ~10% via split cache lines).
#define GEMM_MAIN_LOOP(A_, Bt_, M_, ksteps_, lda_)                              \
  __shared__ f16 As[256 * 64];                                                  \
  __shared__ f16 Bs[128 * 64];                                                  \
  const int tid = threadIdx.x;                                                  \
  const int l = tid & 63;                                                       \
  const int w = tid >> 6;                                                       \
  const int nwg = gridDim.x;            /* 1256 = 8*157 */                      \
  const int s = (blockIdx.x & 7) * (nwg >> 3) + (blockIdx.x >> 3);              \
  const int m0 = (s >> 3) * 256;                                                \
  const int n0 = (s & 7) * 128;                                                 \
  const int wr = (w >> 1) * 64, wc = (w & 1) * 64;                              \
  const int srow = tid >> 3;            /* 0..63 */                             \
  const int slot = tid & 7;                                                     \
  const int lrow = l & 15, g4 = l >> 4;                                         \
  f32x4 acc[4][4] = {};                                                         \
  for (int kt = 0; kt < ksteps_; ++kt) {                                        \
    const int kb = kt * 64;                                                     \
    __syncthreads();                                                            \
    _Pragma("unroll")                                                           \
    for (int c = 0; c < 4; ++c) {                                               \
      int row = c * 64 + srow;                                                  \
      int arow = m0 + row; if (arow >= M_) arow = M_ - 1;                       \
      const f16* g = A_ + (size_t)arow * lda_ + kb + ((slot ^ (row & 7)) * 8);  \
      __builtin_amdgcn_global_load_lds(                                         \
          (const __attribute__((address_space(1))) void*)g,                     \
          (__attribute__((address_space(3))) void*)(As + row * 64 + slot * 8),  \
          16, 0, 0);                                                            \
    }                                                                           \
    _Pragma("unroll")                                                           \
    for (int c = 0; c < 2; ++c) {                                               \
      int row = c * 64 + srow;                                                  \
      const f16* g = Bt_ + (size_t)(n0 + row) * lda_ + kb + ((slot ^ (row & 7)) * 8); \
      __builtin_amdgcn_global_load_lds(                                         \
          (const __attribute__((address_space(1))) void*)g,                     \
          (__attribute__((address_space(3))) void*)(Bs + row * 64 + slot * 8),  \
          16, 0, 0);                                                            \
    }                                                                           \
    __syncthreads();                                                            \
    _Pragma("unroll")                                                           \
    for (int kh = 0; kh < 2; ++kh) {                                            \
      f16x8 af[4], bf[4];                                                       \
      _Pragma("unroll")                                                         \
      for (int m = 0; m < 4; ++m) {                                             \
        int row = wr + m * 16 + lrow;                                           \
        int sl = (g4 + 4 * kh) ^ (row & 7);                                     \
        af[m] = *(const f16x8*)(As + row * 64 + sl * 8);                        \
      }                                                                         \
      _Pragma("unroll")                                                         \
      for (int n = 0; n < 4; ++n) {                                             \
        int row = wc + n * 16 + lrow;                                           \
        int sl = (g4 + 4 * kh) ^ (row & 7);                                     \
        bf[n] = *(const f16x8*)(Bs + row * 64 + sl * 8);                        \
      }                                                                         \
      _Pragma("unroll")                                                         \
      for (int m = 0; m < 4; ++m)                                               \
        _Pragma("unroll")                                                       \
        for (int n = 0; n < 4; ++n)                                             \
          acc[m][n] = __builtin_amdgcn_mfma_f32_16x16x32_f16(af[m], bf[n], acc[m][n], 0, 0, 0); \
    }                                                                           \
  }

// ---------------- GEMM1: C = relu_f16(A @ Bt^T + bias), h1 output
__global__ __launch_bounds__(512, 4) void gemm_f16(
    const f16* __restrict__ A, const f16* __restrict__ Bt,
    const float* __restrict__ bias, f16* __restrict__ C,
    int M, int ksteps, int lda) {
  GEMM_MAIN_LOOP(A, Bt, M, ksteps, lda)

  const int ocol0 = n0 + wc + lrow;
  const int orow0 = m0 + wr + g4 * 4;
#pragma unroll
  for (int m = 0; m < 4; ++m) {
#pragma unroll
    for (int r = 0; r < 4; ++r) {
      int orow = orow0 + m * 16 + r;
      if (orow >= M) continue;
      f16* crow = C + (size_t)orow * DFC;
#pragma unroll
      for (int n = 0; n < 4; ++n) {
        int col = ocol0 + n * 16;
        float v = acc[m][n][r] + bias[col];
        crow[col] = (f16)fmaxf(v, 0.f);
      }
    }
  }
}

// ---------------- GEMM2 with fused fc3: out[m] += sum_col relu(h2)*W3[col]
__global__ __launch_bounds__(512, 4) void gemm2_fc3(
    const f16* __restrict__ A, const f16* __restrict__ Bt,
    const float* __restrict__ bias, const float* __restrict__ W3,
    float* __restrict__ out, int M, int ksteps, int lda) {
  GEMM_MAIN_LOOP(A, Bt, M, ksteps, lda)

  const int ocol0 = n0 + wc + lrow;
  const int orow0 = m0 + wr + g4 * 4;
  float b4[4], w3v[4];
#pragma unroll
  for (int n = 0; n < 4; ++n) {
    b4[n] = bias[ocol0 + n * 16];
    w3v[n] = W3[ocol0 + n * 16];
  }
#pragma unroll
  for (int m = 0; m < 4; ++m) {
#pragma unroll
    for (int r = 0; r < 4; ++r) {
      float sacc = 0.f;
#pragma unroll
      for (int n = 0; n < 4; ++n) {
        float v = fmaxf(acc[m][n][r] + b4[n], 0.f);
        sacc += v * w3v[n];
      }
      sacc += __shfl_xor(sacc, 1);
      sacc += __shfl_xor(sacc, 2);
      sacc += __shfl_xor(sacc, 4);
      sacc += __shfl_xor(sacc, 8);
      int orow = orow0 + m * 16 + r;
      if (lrow == 0 && orow < M) atomicAdd(&out[orow], sacc);
    }
  }
}

extern "C" void kernel_launch(void* const* d_in, const int* in_sizes, int n_in,
                              void* d_out, int out_size, void* d_ws, size_t ws_size,
                              hipStream_t stream) {
  const float* feature = (const float*)d_in[0];
  const float* p       = (const float*)d_in[1];
  const float* feat    = (const float*)d_in[2];
  const float* W_fc1   = (const float*)d_in[3];
  const float* b_fc1   = (const float*)d_in[4];
  const float* W1      = (const float*)d_in[5];
  const float* b1      = (const float*)d_in[6];
  const float* W2      = (const float*)d_in[7];
  const float* b2      = (const float*)d_in[8];
  const float* W3      = (const float*)d_in[9];
  const float* b3      = (const float*)d_in[10];
  float* out = (float*)d_out;

  char* ws = (char*)d_ws;
  f16* x    = (f16*)(ws + 0);                   //  33,554,432 B
  f16* z    = (f16*)(ws + 33554432ULL);         //  87,040,000 B (40000x1088)
  f16* h1   = (f16*)(ws + 120594432ULL);        //  81,920,000 B (40000x1024)
  f16* W1t  = (f16*)(ws + 202514432ULL);        //   2,228,224 B (1024x1088, zeros k>=1032)
  f16* W2t  = (f16*)(ws + 204742656ULL);        //   2,097,152 B (1024x1024)

  // one wide launch: conv (2048) + W1t (1088) + W2t (1024) + fill (157)
  hipLaunchKernelGGL(conv_prep, dim3(4317), dim3(256), 0, stream,
                     feature, W_fc1, b_fc1, x, W1, W1t, W2, W2t, out, b3);
  hipLaunchKernelGGL(sample_kernel, dim3(10000), dim3(256), 0, stream,
                     x, p, feat, z);
  hipLaunchKernelGGL(gemm_f16, dim3(1256), dim3(512), 0, stream,
                     z, W1t, b1, h1, LROWS, KP1 / 64, KP1);
  hipLaunchKernelGGL(gemm2_fc3, dim3(1256), dim3(512), 0, stream,
                     h1, W2t, b2, W3, out, LROWS, DFC / 64, DFC);
}